// Round 5
// baseline (16997.731 us; speedup 1.0000x reference)
//
#include <hip/hip_runtime.h>
#include <math.h>

#define T_SEQ 1024
#define B_SZ  32
#define D_SZ  512
#define H_SZ  256

typedef unsigned short u16;
typedef short v8bf __attribute__((ext_vector_type(8)));
typedef float v4f  __attribute__((ext_vector_type(4)));

// ---------------------------------------------------------------------------
// bf16 helpers (round-to-nearest-even)
// ---------------------------------------------------------------------------
__device__ __forceinline__ unsigned int f2bf(float f)
{
    unsigned int u = __float_as_uint(f);
    return (u + 0x7fffu + ((u >> 16) & 1u)) >> 16;
}
__device__ __forceinline__ u16 f2bfu(float f)
{
    unsigned int u = __float_as_uint(f);
    return (u16)((u + 0x7fffu + ((u >> 16) & 1u)) >> 16);
}
__device__ __forceinline__ float bfu2f(u16 h)
{
    return __uint_as_float(((unsigned int)h) << 16);
}

// async global->LDS, 16B per lane, dest = uniform base + lane*16
__device__ __forceinline__ void gload_lds16(const void* g, void* l)
{
    __builtin_amdgcn_global_load_lds(
        (const __attribute__((address_space(1))) void*)g,
        (__attribute__((address_space(3))) void*)l,
        16, 0, 0);
}

// fast tanh via __expf (|x| <= ~40 safe)
__device__ __forceinline__ float tanh_fast(float x)
{
    float xc = fminf(fmaxf(x, -30.f), 30.f);
    float e = __expf(-2.f * xc);
    return (1.f - e) / (1.f + e);
}

// ---------------------------------------------------------------------------
// Tiled fp32 GEMMs (seq fallback path only).
// ---------------------------------------------------------------------------
#define BM 64
#define BN 64
#define BK 16

__global__ __launch_bounds__(256)
void gemm_nt(const float* __restrict__ A, const float* __restrict__ W,
             const float* __restrict__ bias, float* __restrict__ C,
             int M, int N, int K,
             long long sA, long long sW, long long sC)
{
    int z = blockIdx.z;
    A += (size_t)z * sA; W += (size_t)z * sW; C += (size_t)z * sC;
    int n0 = blockIdx.x * BN;
    int m0 = blockIdx.y * BM;
    int tid = threadIdx.x;
    int tm = tid >> 4, tn = tid & 15;

    __shared__ float As[BK][BM + 4];
    __shared__ float Ws[BK][BN + 4];

    float acc[4][4] = {};

    int lc = tid & 15;
    int lr = tid >> 4;

    for (int k0 = 0; k0 < K; k0 += BK) {
        #pragma unroll
        for (int i = 0; i < 4; ++i) {
            int r = lr + 16 * i;
            As[lc][r] = A[(size_t)(m0 + r) * K + k0 + lc];
            Ws[lc][r] = W[(size_t)(n0 + r) * K + k0 + lc];
        }
        __syncthreads();
        #pragma unroll
        for (int kk = 0; kk < BK; ++kk) {
            float4 a4 = *(const float4*)&As[kk][tm * 4];
            float4 b4 = *(const float4*)&Ws[kk][tn * 4];
            float a[4] = {a4.x, a4.y, a4.z, a4.w};
            float b[4] = {b4.x, b4.y, b4.z, b4.w};
            #pragma unroll
            for (int i = 0; i < 4; ++i)
                #pragma unroll
                for (int j = 0; j < 4; ++j)
                    acc[i][j] = fmaf(a[i], b[j], acc[i][j]);
        }
        __syncthreads();
    }

    float bb[4] = {0.f, 0.f, 0.f, 0.f};
    if (bias) {
        #pragma unroll
        for (int j = 0; j < 4; ++j) bb[j] = bias[n0 + tn * 4 + j];
    }
    #pragma unroll
    for (int i = 0; i < 4; ++i) {
        int m = m0 + tm * 4 + i;
        float4 o;
        o.x = acc[i][0] + bb[0];
        o.y = acc[i][1] + bb[1];
        o.z = acc[i][2] + bb[2];
        o.w = acc[i][3] + bb[3];
        *(float4*)&C[(size_t)m * N + n0 + tn * 4] = o;
    }
}

__global__ __launch_bounds__(256)
void gemm_nn(const float* __restrict__ A, const float* __restrict__ B,
             float* __restrict__ C, int M, int N, int K,
             long long sA, long long sB, long long sC)
{
    int z = blockIdx.z;
    A += (size_t)z * sA; B += (size_t)z * sB; C += (size_t)z * sC;
    int n0 = blockIdx.x * BN;
    int m0 = blockIdx.y * BM;
    int tid = threadIdx.x;
    int tm = tid >> 4, tn = tid & 15;

    __shared__ float As[BK][BM + 4];
    __shared__ float Bs[BK][BN + 4];

    float acc[4][4] = {};

    int lc = tid & 15;
    int lr = tid >> 4;
    int br = tid >> 6;
    int bc = tid & 63;

    for (int k0 = 0; k0 < K; k0 += BK) {
        #pragma unroll
        for (int i = 0; i < 4; ++i) {
            int r = lr + 16 * i;
            As[lc][r] = A[(size_t)(m0 + r) * K + k0 + lc];
        }
        #pragma unroll
        for (int i = 0; i < 4; ++i) {
            int r = br + 4 * i;
            Bs[r][bc] = B[(size_t)(k0 + r) * N + n0 + bc];
        }
        __syncthreads();
        #pragma unroll
        for (int kk = 0; kk < BK; ++kk) {
            float4 a4 = *(const float4*)&As[kk][tm * 4];
            float4 b4 = *(const float4*)&Bs[kk][tn * 4];
            float a[4] = {a4.x, a4.y, a4.z, a4.w};
            float b[4] = {b4.x, b4.y, b4.z, b4.w};
            #pragma unroll
            for (int i = 0; i < 4; ++i)
                #pragma unroll
                for (int j = 0; j < 4; ++j)
                    acc[i][j] = fmaf(a[i], b[j], acc[i][j]);
        }
        __syncthreads();
    }
    #pragma unroll
    for (int i = 0; i < 4; ++i) {
        int m = m0 + tm * 4 + i;
        float4 o;
        o.x = acc[i][0]; o.y = acc[i][1]; o.z = acc[i][2]; o.w = acc[i][3];
        *(float4*)&C[(size_t)m * N + n0 + tn * 4] = o;
    }
}

// ---------------------------------------------------------------------------
// Split-bf16 MFMA NT-GEMM (UNCHANGED from R3/R4 — once the LSTM drops out of
// the top-5, these dispatches surface with counters for an evidence-based
// diagnosis instead of a 4th blind edit).
// ---------------------------------------------------------------------------
template<int EPI>
__global__ __launch_bounds__(256)
void gemm_ms(const u16* __restrict__ Ah, const u16* __restrict__ Al,
             const u16* __restrict__ Bh, const u16* __restrict__ Bl,
             const float* __restrict__ bias,
             float* __restrict__ C, u16* __restrict__ Chi, u16* __restrict__ Clo,
             int M, int N, int K,
             long long sA, long long sB, long long sC)
{
    int z = blockIdx.z;
    Ah += (size_t)z * sA; Al += (size_t)z * sA;
    Bh += (size_t)z * sB; Bl += (size_t)z * sB;
    int n0 = blockIdx.x * 128;
    int m0 = blockIdx.y * 128;
    int t  = threadIdx.x;
    int lane = t & 63, wid = t >> 6;

    __shared__ u16 sA_h[128 * 32];
    __shared__ u16 sA_l[128 * 32];
    __shared__ u16 sB_h[128 * 32];
    __shared__ u16 sB_l[128 * 32];

    int wm = (wid & 1) << 6;
    int wn = (wid >> 1) << 6;
    int fr = lane & 15;
    int g  = lane >> 4;

    v4f acc[4][4];
    #pragma unroll
    for (int i = 0; i < 4; ++i)
        #pragma unroll
        for (int j = 0; j < 4; ++j)
            acc[i][j] = (v4f){0.f, 0.f, 0.f, 0.f};

    int s0 = t;
    int s1 = t + 256;
    int r0 = s0 >> 2, gl0 = (s0 & 3) ^ ((s0 >> 3) & 3);
    int r1 = s1 >> 2, gl1 = (s1 & 3) ^ ((s1 >> 3) & 3);
    int lb0 = (wid << 6) << 3;
    int lb1 = ((wid << 6) + 256) << 3;

    for (int k0 = 0; k0 < K; k0 += 32) {
        size_t gA0 = (size_t)(m0 + r0) * K + k0 + gl0 * 8;
        size_t gA1 = (size_t)(m0 + r1) * K + k0 + gl1 * 8;
        size_t gB0 = (size_t)(n0 + r0) * K + k0 + gl0 * 8;
        size_t gB1 = (size_t)(n0 + r1) * K + k0 + gl1 * 8;
        gload_lds16(Ah + gA0, sA_h + lb0);
        gload_lds16(Ah + gA1, sA_h + lb1);
        gload_lds16(Al + gA0, sA_l + lb0);
        gload_lds16(Al + gA1, sA_l + lb1);
        gload_lds16(Bh + gB0, sB_h + lb0);
        gload_lds16(Bh + gB1, sB_h + lb1);
        gload_lds16(Bl + gB0, sB_l + lb0);
        gload_lds16(Bl + gB1, sB_l + lb1);
        __syncthreads();

        #pragma unroll
        for (int pass = 0; pass < 3; ++pass) {
            const u16* sB_p = (pass == 2) ? sB_l : sB_h;
            const u16* sA_p = (pass == 1) ? sA_l : sA_h;
            v8bf bf[4];
            #pragma unroll
            for (int ni = 0; ni < 4; ++ni) {
                int r = wn + ni * 16 + fr;
                bf[ni] = *(const v8bf*)&sB_p[r * 32 + ((g ^ ((r >> 1) & 3)) << 3)];
            }
            #pragma unroll
            for (int mi = 0; mi < 4; ++mi) {
                int r = wm + mi * 16 + fr;
                v8bf af = *(const v8bf*)&sA_p[r * 32 + ((g ^ ((r >> 1) & 3)) << 3)];
                #pragma unroll
                for (int ni = 0; ni < 4; ++ni)
                    acc[mi][ni] = __builtin_amdgcn_mfma_f32_16x16x32_bf16(
                        af, bf[ni], acc[mi][ni], 0, 0, 0);
            }
        }
        __syncthreads();
    }

    int ocol = lane & 15;
    int orow = (lane >> 4) << 2;
    if (EPI == 1) {
        #pragma unroll
        for (int mi = 0; mi < 4; ++mi) {
            #pragma unroll
            for (int rr = 0; rr < 4; ++rr) {
                int m = m0 + wm + mi * 16 + orow + rr;
                #pragma unroll
                for (int ni = 0; ni < 4; ++ni) {
                    int n = n0 + wn + ni * 16 + ocol;
                    float v = acc[mi][ni][rr];
                    u16 h = f2bfu(v);
                    Chi[(size_t)m * N + n] = h;
                    Clo[(size_t)m * N + n] = f2bfu(v - bfu2f(h));
                }
            }
        }
    } else {
        float* Cz = C + (size_t)z * sC;
        float bb[4] = {0.f, 0.f, 0.f, 0.f};
        if (bias) {
            #pragma unroll
            for (int ni = 0; ni < 4; ++ni) bb[ni] = bias[n0 + wn + ni * 16 + ocol];
        }
        #pragma unroll
        for (int mi = 0; mi < 4; ++mi) {
            #pragma unroll
            for (int rr = 0; rr < 4; ++rr) {
                int m = m0 + wm + mi * 16 + orow + rr;
                #pragma unroll
                for (int ni = 0; ni < 4; ++ni) {
                    int n = n0 + wn + ni * 16 + ocol;
                    Cz[(size_t)m * N + n] = acc[mi][ni][rr] + bb[ni];
                }
            }
        }
    }
}

// ---------------------------------------------------------------------------
// fp32 -> bf16 hi/lo split, 4 elems per thread (exact-grid launch).
// ---------------------------------------------------------------------------
__global__ __launch_bounds__(256)
void convert_split(const float4* __restrict__ in,
                   ushort4* __restrict__ hi, ushort4* __restrict__ lo)
{
    size_t i = (size_t)blockIdx.x * 256 + threadIdx.x;
    float4 v = in[i];
    ushort4 h, l;
    h.x = f2bfu(v.x); l.x = f2bfu(v.x - bfu2f(h.x));
    h.y = f2bfu(v.y); l.y = f2bfu(v.y - bfu2f(h.y));
    h.z = f2bfu(v.z); l.z = f2bfu(v.z - bfu2f(h.z));
    h.w = f2bfu(v.w); l.w = f2bfu(v.w - bfu2f(h.w));
    hi[i] = h;
    lo[i] = l;
}

// ---------------------------------------------------------------------------
// Per-batch transpose of xe fp32 [b][t][D] -> xeT bf16 hi/lo [b][d][T].
// ---------------------------------------------------------------------------
__global__ __launch_bounds__(256)
void transpose_split_xe(const float* __restrict__ xe,
                        u16* __restrict__ Th, u16* __restrict__ Tl)
{
    int b = blockIdx.z;
    const float* X = xe + (size_t)b * T_SEQ * D_SZ;
    u16* TH = Th + (size_t)b * T_SEQ * D_SZ;
    u16* TL = Tl + (size_t)b * T_SEQ * D_SZ;
    int t0 = blockIdx.x << 5, d0 = blockIdx.y << 5;

    __shared__ float tile[32][33];
    int tx = threadIdx.x & 31, ty = threadIdx.x >> 5;

    #pragma unroll
    for (int i = 0; i < 4; ++i)
        tile[ty + (i << 3)][tx] = X[(size_t)(t0 + ty + (i << 3)) * D_SZ + d0 + tx];
    __syncthreads();
    #pragma unroll
    for (int i = 0; i < 4; ++i) {
        int dd = ty + (i << 3);
        float v = tile[tx][dd];
        u16 h = f2bfu(v);
        TH[(size_t)(d0 + dd) * T_SEQ + t0 + tx] = h;
        TL[(size_t)(d0 + dd) * T_SEQ + t0 + tx] = f2bfu(v - bfu2f(h));
    }
}

// ---------------------------------------------------------------------------
// Pack W_hh [4H,H] fp32 -> bf16 gate/k-pair packed (seq-fallback LSTM only).
// ---------------------------------------------------------------------------
__global__ __launch_bounds__(256)
void pack_whh_bf16(const float* __restrict__ Wf, const float* __restrict__ Wb,
                   uint4* __restrict__ Wpf, uint4* __restrict__ Wpb)
{
    int idx = blockIdx.x * 256 + threadIdx.x;
    int u = idx & (H_SZ - 1);
    int p = idx >> 8;
    uint4 a, b;
    unsigned int* pa = (unsigned int*)&a;
    unsigned int* pb = (unsigned int*)&b;
    #pragma unroll
    for (int g = 0; g < 4; ++g) {
        size_t row = (size_t)(g * H_SZ + u) * H_SZ;
        pa[g] = f2bf(Wf[row + 2 * p]) | (f2bf(Wf[row + 2 * p + 1]) << 16);
        pb[g] = f2bf(Wb[row + 2 * p]) | (f2bf(Wb[row + 2 * p + 1]) << 16);
    }
    Wpf[idx] = a;
    Wpb[idx] = b;
}

// ---------------------------------------------------------------------------
// Plain row-major bf16 cast of W_hh [1024,256] for the MFMA LSTM (both dirs).
// 4 elems/thread, grid = 4H*H/1024 = 256 blocks.
// ---------------------------------------------------------------------------
__global__ __launch_bounds__(256)
void pack_w_rows(const float4* __restrict__ Wf, const float4* __restrict__ Wb,
                 ushort4* __restrict__ Of, ushort4* __restrict__ Ob)
{
    size_t i = (size_t)blockIdx.x * 256 + threadIdx.x;
    float4 a = Wf[i], b = Wb[i];
    ushort4 oa, ob;
    oa.x = f2bfu(a.x); oa.y = f2bfu(a.y); oa.z = f2bfu(a.z); oa.w = f2bfu(a.w);
    ob.x = f2bfu(b.x); ob.y = f2bfu(b.y); ob.z = f2bfu(b.z); ob.w = f2bfu(b.w);
    Of[i] = oa;
    Ob[i] = ob;
}

// ---------------------------------------------------------------------------
// MFMA LSTM recurrence (fused path).
// R0-R4 floor analysis: the old 1-batch-per-block design re-read the full
// 512KB packed W per block per step (3.3us VMEM floor at per-CU L2-return BW)
// on top of ~2us/step VALU (unpack+fma through 4 SIMDs) -> ~7us/step.
// New design: 4 blocks = (2 dirs x 2 groups of 16 batches). Per step per
// block: S[16,1024] = h[16,256] @ W^T via mfma_16x16x32 (M=16 exactly).
//  - W traffic unchanged per CU (512KB/step) but covers 16 batches (16x less
//    redundancy); VALU work moves to the matrix pipe (hidden under stream).
//  - h precision preserved: h = hHi + hLo bf16 split, 2 MFMA per tile
//    (B shared), so recurrence math ~= bf16-W x fp32-h as before.
//  - h in XOR-swizzled LDS (writer/reader same involution); gate exchange
//    via padded LDS [16][1028] (2-way conflicts only).
// 512 threads = 8 waves -> 256-VGPR cap (no 1024-block 128-cap fight).
// ---------------------------------------------------------------------------
__global__ __launch_bounds__(512, 2)
void lstm_mfma(const float* __restrict__ xgA, const u16* __restrict__ WA,
               const float* __restrict__ xgB, const u16* __restrict__ WB,
               float* __restrict__ xe)
{
    int bi  = blockIdx.x;          // 0..3
    int dir = bi >> 1;
    int b0  = (bi & 1) * 16;
    const float* xg = dir ? xgB : xgA;
    const u16*  W   = dir ? WB : WA;

    int tid  = threadIdx.x;
    int lane = tid & 63, wv = tid >> 6;
    int wn   = wv << 7;            // wave's 128-wide N-slice
    int fr   = lane & 15;          // A row (batch) / B col-in-tile
    int kg   = lane >> 4;          // k-group (0..3)

    __shared__ u16  hHi[16 * 256];         //  8 KB, XOR-swizzled 16B slots
    __shared__ u16  hLo[16 * 256];         //  8 KB
    __shared__ float gate[16][1024 + 4];   // ~66 KB, stride 1028 (2-way only)

    for (int i = tid; i < 16 * 256; i += 512) { hHi[i] = 0; hLo[i] = 0; }

    // B pointers: 8 n-tiles per wave; per k-step advance = 32 elems (imm)
    const u16* bp[8];
    #pragma unroll
    for (int ni = 0; ni < 8; ++ni)
        bp[ni] = W + (size_t)(wn + ni * 16 + fr) * 256 + kg * 8;

    // owner decomposition: thread = (u, bh); owns 8 local batches
    int u  = tid & 255;
    int bh = tid >> 8;
    float c8[8];
    #pragma unroll
    for (int j = 0; j < 8; ++j) c8[j] = 0.f;

    __syncthreads();

    for (int s = 0; s < T_SEQ; ++s) {
        int t = dir ? (T_SEQ - 1 - s) : s;

        // prefetch xg for owner phase (latency hidden under MFMA+stream)
        float pxi[8], pxf[8], pxg[8], pxo[8];
        #pragma unroll
        for (int j = 0; j < 8; ++j) {
            int bl = bh * 8 + j;
            const float* row = xg + ((size_t)(b0 + bl) * T_SEQ + t) * (4 * H_SZ);
            pxi[j] = row[u];
            pxf[j] = row[256 + u];
            pxg[j] = row[512 + u];
            pxo[j] = row[768 + u];
        }

        v4f accH[8], accL[8];
        #pragma unroll
        for (int ni = 0; ni < 8; ++ni) {
            accH[ni] = (v4f){0.f, 0.f, 0.f, 0.f};
            accL[ni] = (v4f){0.f, 0.f, 0.f, 0.f};
        }

        #pragma unroll
        for (int ks = 0; ks < 8; ++ks) {
            // A-frags from swizzled LDS: row=fr, kslot = ks*4+kg, phys ^= fr&7
            int aoff = fr * 512 + ((((ks << 2) + kg) ^ (fr & 7)) << 4);
            v8bf aH = *(const v8bf*)((const char*)hHi + aoff);
            v8bf aL = *(const v8bf*)((const char*)hLo + aoff);
            #pragma unroll
            for (int ni = 0; ni < 8; ++ni) {
                v8bf bf = *(const v8bf*)(bp[ni] + ks * 32);
                accH[ni] = __builtin_amdgcn_mfma_f32_16x16x32_bf16(aH, bf, accH[ni], 0, 0, 0);
                accL[ni] = __builtin_amdgcn_mfma_f32_16x16x32_bf16(aL, bf, accL[ni], 0, 0, 0);
            }
        }

        // C-frag: row = 4*kg + reg (batch), col = wn + ni*16 + fr (gate idx)
        int orow = kg << 2;
        #pragma unroll
        for (int ni = 0; ni < 8; ++ni) {
            #pragma unroll
            for (int r = 0; r < 4; ++r)
                gate[orow + r][wn + ni * 16 + fr] = accH[ni][r] + accL[ni][r];
        }
        __syncthreads();   // gates visible; all h reads of step s done

        #pragma unroll
        for (int j = 0; j < 8; ++j) {
            int bl = bh * 8 + j;
            float ai = pxi[j] + gate[bl][u];
            float af = pxf[j] + gate[bl][256 + u];
            float ag = pxg[j] + gate[bl][512 + u];
            float ao = pxo[j] + gate[bl][768 + u];
            float ig = 1.f / (1.f + __expf(-ai));
            float fg = 1.f / (1.f + __expf(-af));
            float gv = tanh_fast(ag);
            float og = 1.f / (1.f + __expf(-ao));
            c8[j] = fg * c8[j] + ig * gv;
            float hv = og * tanh_fast(c8[j]);
            xe[((size_t)(b0 + bl) * T_SEQ + t) * D_SZ + dir * H_SZ + u] = hv;
            u16 hh = f2bfu(hv);
            u16 hl = f2bfu(hv - bfu2f(hh));
            int hoff = bl * 512 + ((((u >> 3) ^ (bl & 7)) << 4)) + ((u & 7) << 1);
            *(u16*)((char*)hHi + hoff) = hh;
            *(u16*)((char*)hLo + hoff) = hl;
        }
        __syncthreads();   // new h visible before next step's A-reads
    }
}

// ---------------------------------------------------------------------------
// Legacy LSTM (seq fallback path only).
// ---------------------------------------------------------------------------
__global__ __launch_bounds__(1024)
void lstm_bf16(const float* __restrict__ xgA, const uint4* __restrict__ WpA,
               const float* __restrict__ xgB, const uint4* __restrict__ WpB,
               float* __restrict__ xe, int d0, int fused)
{
    int i = blockIdx.x;
    int b, dir;
    if (fused) {
        int j = i & 7, m = i >> 3;
        dir = j >> 2;
        b   = (j & 3) * 8 + m;
    } else {
        b   = (i & 3) * 8 + (i >> 2);
        dir = d0;
    }
    const float* xg = dir ? xgB : xgA;
    const uint4* Wp = dir ? WpB : WpA;

    int tid   = threadIdx.x;
    int u     = tid & (H_SZ - 1);
    int slice = tid >> 8;
    int p0    = slice << 5;

    __shared__ float  hs[H_SZ];
    __shared__ float4 part[4][H_SZ];

    uint4 wres[16];
    {
        const uint4* wb = Wp + (size_t)p0 * H_SZ + u;
        #pragma unroll
        for (int q = 0; q < 16; ++q) wres[q] = wb[q * H_SZ];
    }
    const uint4* wstream = Wp + (size_t)(p0 + 16) * H_SZ + u;

    if (tid < H_SZ) hs[tid] = 0.f;
    float c = 0.f;
    __syncthreads();

    for (int s = 0; s < T_SEQ; ++s) {
        int t = dir ? (T_SEQ - 1 - s) : s;

        float xi = 0.f, xf = 0.f, xgv = 0.f, xo = 0.f;
        if (tid < H_SZ) {
            const float* row = xg + ((size_t)b * T_SEQ + t) * (4 * H_SZ);
            xi  = row[u];
            xf  = row[H_SZ + u];
            xgv = row[2 * H_SZ + u];
            xo  = row[3 * H_SZ + u];
        }

        float4 acc; acc.x = 0.f; acc.y = 0.f; acc.z = 0.f; acc.w = 0.f;

        #define DOT_PAIR(WQ, P)                                             \
        {                                                                   \
            float2 hp = *(const float2*)&hs[2 * (P)];                       \
            const unsigned int* wc = (const unsigned int*)&(WQ);            \
            _Pragma("unroll")                                               \
            for (int g = 0; g < 4; ++g) {                                   \
                float wlo = __uint_as_float(wc[g] << 16);                   \
                float whi = __uint_as_float(wc[g] & 0xffff0000u);           \
                ((float*)&acc)[g] =                                         \
                    fmaf(whi, hp.y, fmaf(wlo, hp.x, ((float*)&acc)[g]));    \
            }                                                               \
        }

        #pragma unroll
        for (int q = 0; q < 16; ++q) {
            DOT_PAIR(wres[q], p0 + q);
        }
        #pragma unroll
        for (int q = 0; q < 16; ++q) {
            int qr = (q + s) & 15;
            uint4 wq = wstream[(size_t)qr * H_SZ];
            DOT_PAIR(wq, p0 + 16 + qr);
        }
        #undef DOT_PAIR

        part[slice][u] = acc;
        __syncthreads();

        if (tid < H_SZ) {
            float4 pp0 = part[0][u], pp1 = part[1][u], pp2 = part[2][u], pp3 = part[3][u];
            float ai = xi  + pp0.x + pp1.x + pp2.x + pp3.x;
            float af = xf  + pp0.y + pp1.y + pp2.y + pp3.y;
            float ag = xgv + pp0.z + pp1.z + pp2.z + pp3.z;
            float ao = xo  + pp0.w + pp1.w + pp2.w + pp3.w;
            float ig = 1.f / (1.f + __expf(-ai));
            float fg = 1.f / (1.f + __expf(-af));
            float gg = tanh_fast(ag);
            float og = 1.f / (1.f + __expf(-ao));
            c = fg * c + ig * gg;
            float h = og * tanh_fast(c);
            hs[u] = h;
            xe[((size_t)b * T_SEQ + t) * D_SZ + dir * H_SZ + u] = h;
        }
        __syncthreads();
    }
}

// ---------------------------------------------------------------------------
// Masked row softmax (fp32 in place).
// ---------------------------------------------------------------------------
__global__ __launch_bounds__(256)
void softmax_rows(float* __restrict__ L, const void* __restrict__ maskraw)
{
    const unsigned char* mu8 = (const unsigned char*)maskraw;
    const int*           mi32 = (const int*)maskraw;
    bool layout_u8 = (mu8[1023] != 0);

    int lane = threadIdx.x & 63;
    int wid  = threadIdx.x >> 6;
    int row  = (blockIdx.x << 2) + wid;
    float* p = L + (size_t)row * T_SEQ;

    int mval = layout_u8 ? (int)mu8[row] : mi32[row];

    if (mval != 0) {
        const float inv = 1.0f / (float)T_SEQ;
        for (int j = lane; j < T_SEQ; j += 64) p[j] = inv;
        return;
    }

    float v[16];
    float m = -1e30f;
    #pragma unroll
    for (int u = 0; u < 16; ++u) {
        v[u] = p[lane + (u << 6)];
        m = fmaxf(m, v[u]);
    }
    #pragma unroll
    for (int s = 32; s; s >>= 1) m = fmaxf(m, __shfl_xor(m, s, 64));

    float sum = 0.f;
    #pragma unroll
    for (int u = 0; u < 16; ++u) {
        v[u] = __expf(v[u] - m);
        sum += v[u];
    }
    #pragma unroll
    for (int s = 32; s; s >>= 1) sum += __shfl_xor(sum, s, 64);

    float inv = 1.0f / sum;
    #pragma unroll
    for (int u = 0; u < 16; ++u) p[lane + (u << 6)] = v[u] * inv;
}

// ---------------------------------------------------------------------------
// Fused-path workspace plan (ws = 320 MiB exactly):
//   phase 1 (pre-LSTM):  x_hi [0,32) x_lo [32,64) | xg_f [64,192) | xg_b [192,320)
//   phase 2 (LSTM):      xe fp32 overwrites [0,64)  (x split dead)
//   phase 3 (attn):      xe_hi [64,96) xe_lo [96,128)   (xg_f dead)
//                        pj_hi [128,160) pj_lo [160,192)
//                        L fp32 [192,320)               (xg_b dead)
//   phase 4 (post-sm):   xT_hi/lo at [128,192)          (pj dead)
//                        L_hi [0,64) L_lo [64,128)
// d_out scratch (64 MiB, dead before final out-GEMM writes it):
//   WB_f [0,0.5) WB_b [0.5,1) | Wihf_hi [1,2) Wihf_lo [2,3)
//   | Wihb_hi [3,4) Wihb_lo [4,5) | Wl_hi [5,5.5) Wl_lo [5.5,6)
// ---------------------------------------------------------------------------
extern "C" void kernel_launch(void* const* d_in, const int* in_sizes, int n_in,
                              void* d_out, int out_size, void* d_ws, size_t ws_size,
                              hipStream_t stream)
{
    const float* x     = (const float*)d_in[0];
    const void*  xmask = d_in[1];
    const float* Wih_f = (const float*)d_in[2];
    const float* Whh_f = (const float*)d_in[3];
    const float* b_f   = (const float*)d_in[4];
    const float* Wih_b = (const float*)d_in[5];
    const float* Whh_b = (const float*)d_in[6];
    const float* b_b   = (const float*)d_in[7];
    const float* W_l   = (const float*)d_in[8];
    float* out = (float*)d_out;

    char* ws = (char*)d_ws;
    const size_t MB1 = (size_t)1 << 20;
    const size_t SZ_XE = (size_t)B_SZ * T_SEQ * D_SZ * sizeof(float);      //  64 MiB
    const size_t SZ_XG = (size_t)B_SZ * T_SEQ * 4 * H_SZ * sizeof(float);  // 128 MiB
    bool fused = ws_size >= SZ_XE + 2 * SZ_XG;

    const int MT = B_SZ * T_SEQ;                       // 32768
    const long long sTD = (long long)T_SEQ * D_SZ;     // 524288
    const long long sTT = (long long)T_SEQ * T_SEQ;    // 1048576

    if (fused) {
        u16* x_hi  = (u16*)(ws);
        u16* x_lo  = (u16*)(ws + 32 * MB1);
        float* xg_f = (float*)(ws + 64 * MB1);
        float* xg_b = (float*)(ws + 192 * MB1);
        float* xe   = (float*)(ws);                  // phase 2
        u16* xe_hi = (u16*)(ws + 64 * MB1);
        u16* xe_lo = (u16*)(ws + 96 * MB1);
        u16* pj_hi = (u16*)(ws + 128 * MB1);
        u16* pj_lo = (u16*)(ws + 160 * MB1);
        float* L   = (float*)(ws + 192 * MB1);
        u16* xT_hi = pj_hi;                          // phase 4 reuse
        u16* xT_lo = pj_lo;
        u16* L_hi  = (u16*)(ws);
        u16* L_lo  = (u16*)(ws + 64 * MB1);

        u16* WB_f    = (u16*)d_out;
        u16* WB_b    = (u16*)((char*)d_out + (MB1 >> 1));
        u16* Wihf_hi = (u16*)((char*)d_out + 1 * MB1);
        u16* Wihf_lo = (u16*)((char*)d_out + 2 * MB1);
        u16* Wihb_hi = (u16*)((char*)d_out + 3 * MB1);
        u16* Wihb_lo = (u16*)((char*)d_out + 4 * MB1);
        u16* Wl_hi   = (u16*)((char*)d_out + 5 * MB1);
        u16* Wl_lo   = (u16*)((char*)d_out + 5 * MB1 + (MB1 >> 1));

        // 1. packs/splits: W_hh rows (MFMA LSTM), x, W_ih, W_l
        pack_w_rows<<<dim3((4 * H_SZ * H_SZ) / 1024), dim3(256), 0, stream>>>(
            (const float4*)Whh_f, (const float4*)Whh_b,
            (ushort4*)WB_f, (ushort4*)WB_b);
        convert_split<<<dim3((MT * D_SZ) / 1024), dim3(256), 0, stream>>>(
            (const float4*)x, (ushort4*)x_hi, (ushort4*)x_lo);
        convert_split<<<dim3((4 * H_SZ * D_SZ) / 1024), dim3(256), 0, stream>>>(
            (const float4*)Wih_f, (ushort4*)Wihf_hi, (ushort4*)Wihf_lo);
        convert_split<<<dim3((4 * H_SZ * D_SZ) / 1024), dim3(256), 0, stream>>>(
            (const float4*)Wih_b, (ushort4*)Wihb_hi, (ushort4*)Wihb_lo);
        convert_split<<<dim3((D_SZ * D_SZ) / 1024), dim3(256), 0, stream>>>(
            (const float4*)W_l, (ushort4*)Wl_hi, (ushort4*)Wl_lo);

        // 2. xg projections (MFMA split, fp32 out + bias)
        gemm_ms<0><<<dim3((4 * H_SZ) / 128, MT / 128, 1), dim3(256), 0, stream>>>(
            x_hi, x_lo, Wihf_hi, Wihf_lo, b_f, xg_f, nullptr, nullptr,
            MT, 4 * H_SZ, D_SZ, 0, 0, 0);
        gemm_ms<0><<<dim3((4 * H_SZ) / 128, MT / 128, 1), dim3(256), 0, stream>>>(
            x_hi, x_lo, Wihb_hi, Wihb_lo, b_b, xg_b, nullptr, nullptr,
            MT, 4 * H_SZ, D_SZ, 0, 0, 0);

        // 3. BiLSTM via MFMA (4 blocks: 2 dirs x 2 groups of 16 batches)
        lstm_mfma<<<dim3(4), dim3(512), 0, stream>>>(
            xg_f, WB_f, xg_b, WB_b, xe);

        // 4. xe -> hi/lo (xg_f dead)
        convert_split<<<dim3((MT * D_SZ) / 1024), dim3(256), 0, stream>>>(
            (const float4*)xe, (ushort4*)xe_hi, (ushort4*)xe_lo);

        // 5. proj = xe @ W_l^T  (epilogue emits split pair)
        gemm_ms<1><<<dim3(D_SZ / 128, MT / 128, 1), dim3(256), 0, stream>>>(
            xe_hi, xe_lo, Wl_hi, Wl_lo, nullptr, nullptr, pj_hi, pj_lo,
            MT, D_SZ, D_SZ, 0, 0, 0);

        // 6. scores L[b] = proj[b] @ xe[b]^T  (fp32 out, xg_b dead)
        gemm_ms<0><<<dim3(T_SEQ / 128, T_SEQ / 128, B_SZ), dim3(256), 0, stream>>>(
            pj_hi, pj_lo, xe_hi, xe_lo, nullptr, L, nullptr, nullptr,
            T_SEQ, T_SEQ, D_SZ, sTD, sTD, sTT);

        // 7. masked softmax (fp32, in place)
        softmax_rows<<<dim3(MT / 4), dim3(256), 0, stream>>>(L, xmask);

        // 8. xeT hi/lo for out GEMM (pj dead; must precede L-convert)
        transpose_split_xe<<<dim3(T_SEQ / 32, D_SZ / 32, B_SZ), dim3(256), 0, stream>>>(
            xe, xT_hi, xT_lo);

        // 9. L -> hi/lo (xe fp32 + xe split dead)
        convert_split<<<dim3((MT * T_SEQ) / 1024), dim3(256), 0, stream>>>(
            (const float4*)L, (ushort4*)L_hi, (ushort4*)L_lo);

        // 10. out[b] = A[b] @ xe[b]  ==  NT(L split, xeT split)
        gemm_ms<0><<<dim3(D_SZ / 128, T_SEQ / 128, B_SZ), dim3(256), 0, stream>>>(
            L_hi, L_lo, xT_hi, xT_lo, nullptr, out, nullptr, nullptr,
            T_SEQ, D_SZ, T_SEQ, sTT, sTD, sTD);
    } else {
        // -------- fp32 fallback (ws < 320 MiB) --------
        uint4* Wpf = (uint4*)d_out;
        uint4* Wpb = (uint4*)d_out + 128 * H_SZ;
        float* xe   = (float*)(ws);
        float* xg_f = (float*)(ws + SZ_XE);
        float* xg_b = xg_f;
        float* L    = xg_f;
        float* proj = out;

        pack_whh_bf16<<<dim3((128 * H_SZ) / 256), dim3(256), 0, stream>>>(
            Whh_f, Whh_b, Wpf, Wpb);
        gemm_nt<<<dim3((4 * H_SZ) / BN, MT / BM, 1), dim3(256), 0, stream>>>(
            x, Wih_f, b_f, xg_f, MT, 4 * H_SZ, D_SZ, 0, 0, 0);
        lstm_bf16<<<dim3(B_SZ), dim3(1024), 0, stream>>>(
            xg_f, Wpf, xg_f, Wpf, xe, 0, 0);
        gemm_nt<<<dim3((4 * H_SZ) / BN, MT / BM, 1), dim3(256), 0, stream>>>(
            x, Wih_b, b_b, xg_b, MT, 4 * H_SZ, D_SZ, 0, 0, 0);
        lstm_bf16<<<dim3(B_SZ), dim3(1024), 0, stream>>>(
            xg_b, Wpb, xg_b, Wpb, xe, 1, 0);

        gemm_nt<<<dim3(D_SZ / BN, MT / BM, 1), dim3(256), 0, stream>>>(
            xe, W_l, nullptr, proj, MT, D_SZ, D_SZ, 0, 0, 0);
        gemm_nt<<<dim3(T_SEQ / BN, T_SEQ / BM, B_SZ), dim3(256), 0, stream>>>(
            proj, xe, nullptr, L, T_SEQ, T_SEQ, D_SZ, sTD, sTD, sTT);
        softmax_rows<<<dim3(MT / 4), dim3(256), 0, stream>>>(L, xmask);
        gemm_nn<<<dim3(D_SZ / BN, T_SEQ / BM, B_SZ), dim3(256), 0, stream>>>(
            L, xe, out, T_SEQ, D_SZ, T_SEQ, sTT, sTD, sTD);
    }
}

// Round 7
// 13770.610 us; speedup vs baseline: 1.2343x; 1.2343x over previous
//
#include <hip/hip_runtime.h>
#include <math.h>

#define T_SEQ 1024
#define B_SZ  32
#define D_SZ  512
#define H_SZ  256

typedef unsigned short u16;
typedef short v8bf __attribute__((ext_vector_type(8)));
typedef float v4f  __attribute__((ext_vector_type(4)));

// ---------------------------------------------------------------------------
// bf16 helpers (round-to-nearest-even)
// ---------------------------------------------------------------------------
__device__ __forceinline__ unsigned int f2bf(float f)
{
    unsigned int u = __float_as_uint(f);
    return (u + 0x7fffu + ((u >> 16) & 1u)) >> 16;
}
__device__ __forceinline__ u16 f2bfu(float f)
{
    unsigned int u = __float_as_uint(f);
    return (u16)((u + 0x7fffu + ((u >> 16) & 1u)) >> 16);
}
__device__ __forceinline__ float bfu2f(u16 h)
{
    return __uint_as_float(((unsigned int)h) << 16);
}

// async global->LDS, 16B per lane, dest = uniform base + lane*16
__device__ __forceinline__ void gload_lds16(const void* g, void* l)
{
    __builtin_amdgcn_global_load_lds(
        (const __attribute__((address_space(1))) void*)g,
        (__attribute__((address_space(3))) void*)l,
        16, 0, 0);
}

// fast tanh via __expf (|x| <= ~40 safe); validated by the seq path runs
__device__ __forceinline__ float tanh_fast(float x)
{
    float xc = fminf(fmaxf(x, -30.f), 30.f);
    float e = __expf(-2.f * xc);
    return (1.f - e) / (1.f + e);
}

// ---------------------------------------------------------------------------
// Tiled fp32 GEMMs (seq fallback path only).
// ---------------------------------------------------------------------------
#define BM 64
#define BN 64
#define BK 16

__global__ __launch_bounds__(256)
void gemm_nt(const float* __restrict__ A, const float* __restrict__ W,
             const float* __restrict__ bias, float* __restrict__ C,
             int M, int N, int K,
             long long sA, long long sW, long long sC)
{
    int z = blockIdx.z;
    A += (size_t)z * sA; W += (size_t)z * sW; C += (size_t)z * sC;
    int n0 = blockIdx.x * BN;
    int m0 = blockIdx.y * BM;
    int tid = threadIdx.x;
    int tm = tid >> 4, tn = tid & 15;

    __shared__ float As[BK][BM + 4];
    __shared__ float Ws[BK][BN + 4];

    float acc[4][4] = {};

    int lc = tid & 15;
    int lr = tid >> 4;

    for (int k0 = 0; k0 < K; k0 += BK) {
        #pragma unroll
        for (int i = 0; i < 4; ++i) {
            int r = lr + 16 * i;
            As[lc][r] = A[(size_t)(m0 + r) * K + k0 + lc];
            Ws[lc][r] = W[(size_t)(n0 + r) * K + k0 + lc];
        }
        __syncthreads();
        #pragma unroll
        for (int kk = 0; kk < BK; ++kk) {
            float4 a4 = *(const float4*)&As[kk][tm * 4];
            float4 b4 = *(const float4*)&Ws[kk][tn * 4];
            float a[4] = {a4.x, a4.y, a4.z, a4.w};
            float b[4] = {b4.x, b4.y, b4.z, b4.w};
            #pragma unroll
            for (int i = 0; i < 4; ++i)
                #pragma unroll
                for (int j = 0; j < 4; ++j)
                    acc[i][j] = fmaf(a[i], b[j], acc[i][j]);
        }
        __syncthreads();
    }

    float bb[4] = {0.f, 0.f, 0.f, 0.f};
    if (bias) {
        #pragma unroll
        for (int j = 0; j < 4; ++j) bb[j] = bias[n0 + tn * 4 + j];
    }
    #pragma unroll
    for (int i = 0; i < 4; ++i) {
        int m = m0 + tm * 4 + i;
        float4 o;
        o.x = acc[i][0] + bb[0];
        o.y = acc[i][1] + bb[1];
        o.z = acc[i][2] + bb[2];
        o.w = acc[i][3] + bb[3];
        *(float4*)&C[(size_t)m * N + n0 + tn * 4] = o;
    }
}

__global__ __launch_bounds__(256)
void gemm_nn(const float* __restrict__ A, const float* __restrict__ B,
             float* __restrict__ C, int M, int N, int K,
             long long sA, long long sB, long long sC)
{
    int z = blockIdx.z;
    A += (size_t)z * sA; B += (size_t)z * sB; C += (size_t)z * sC;
    int n0 = blockIdx.x * BN;
    int m0 = blockIdx.y * BM;
    int tid = threadIdx.x;
    int tm = tid >> 4, tn = tid & 15;

    __shared__ float As[BK][BM + 4];
    __shared__ float Bs[BK][BN + 4];

    float acc[4][4] = {};

    int lc = tid & 15;
    int lr = tid >> 4;
    int br = tid >> 6;
    int bc = tid & 63;

    for (int k0 = 0; k0 < K; k0 += BK) {
        #pragma unroll
        for (int i = 0; i < 4; ++i) {
            int r = lr + 16 * i;
            As[lc][r] = A[(size_t)(m0 + r) * K + k0 + lc];
        }
        #pragma unroll
        for (int i = 0; i < 4; ++i) {
            int r = br + 4 * i;
            Bs[r][bc] = B[(size_t)(k0 + r) * N + n0 + bc];
        }
        __syncthreads();
        #pragma unroll
        for (int kk = 0; kk < BK; ++kk) {
            float4 a4 = *(const float4*)&As[kk][tm * 4];
            float4 b4 = *(const float4*)&Bs[kk][tn * 4];
            float a[4] = {a4.x, a4.y, a4.z, a4.w};
            float b[4] = {b4.x, b4.y, b4.z, b4.w};
            #pragma unroll
            for (int i = 0; i < 4; ++i)
                #pragma unroll
                for (int j = 0; j < 4; ++j)
                    acc[i][j] = fmaf(a[i], b[j], acc[i][j]);
        }
        __syncthreads();
    }
    #pragma unroll
    for (int i = 0; i < 4; ++i) {
        int m = m0 + tm * 4 + i;
        float4 o;
        o.x = acc[i][0]; o.y = acc[i][1]; o.z = acc[i][2]; o.w = acc[i][3];
        *(float4*)&C[(size_t)m * N + n0 + tn * 4] = o;
    }
}

// ---------------------------------------------------------------------------
// Split-bf16 MFMA NT-GEMM (m97 structure: global_load_lds width-16, linear
// LDS + slot swizzle, 2-barrier K-loop).
//   C[M,N] = (Ah+Al)[M,K] @ (Bh+Bl)[N,K]^T   (3 passes: HH, LH, HL; within a
//   pass all 16 MFMAs hit distinct accumulators)
// Tile 128x128x32, 256 thr = 4 waves (2x2 of 64x64), 16x16x32 bf16 frags.
// EPI 0: C fp32 (+ optional bias[n]).   EPI 1: C -> bf16 hi/lo pair.
// ---------------------------------------------------------------------------
template<int EPI>
__global__ __launch_bounds__(256)
void gemm_ms(const u16* __restrict__ Ah, const u16* __restrict__ Al,
             const u16* __restrict__ Bh, const u16* __restrict__ Bl,
             const float* __restrict__ bias,
             float* __restrict__ C, u16* __restrict__ Chi, u16* __restrict__ Clo,
             int M, int N, int K,
             long long sA, long long sB, long long sC)
{
    int z = blockIdx.z;
    Ah += (size_t)z * sA; Al += (size_t)z * sA;
    Bh += (size_t)z * sB; Bl += (size_t)z * sB;
    int n0 = blockIdx.x * 128;
    int m0 = blockIdx.y * 128;
    int t  = threadIdx.x;
    int lane = t & 63, wid = t >> 6;

    __shared__ u16 sA_h[128 * 32];
    __shared__ u16 sA_l[128 * 32];
    __shared__ u16 sB_h[128 * 32];
    __shared__ u16 sB_l[128 * 32];

    int wm = (wid & 1) << 6;
    int wn = (wid >> 1) << 6;
    int fr = lane & 15;
    int g  = lane >> 4;

    v4f acc[4][4];
    #pragma unroll
    for (int i = 0; i < 4; ++i)
        #pragma unroll
        for (int j = 0; j < 4; ++j)
            acc[i][j] = (v4f){0.f, 0.f, 0.f, 0.f};

    int s0 = t;
    int s1 = t + 256;
    int r0 = s0 >> 2, gl0 = (s0 & 3) ^ ((s0 >> 3) & 3);
    int r1 = s1 >> 2, gl1 = (s1 & 3) ^ ((s1 >> 3) & 3);
    int lb0 = (wid << 6) << 3;
    int lb1 = ((wid << 6) + 256) << 3;

    for (int k0 = 0; k0 < K; k0 += 32) {
        size_t gA0 = (size_t)(m0 + r0) * K + k0 + gl0 * 8;
        size_t gA1 = (size_t)(m0 + r1) * K + k0 + gl1 * 8;
        size_t gB0 = (size_t)(n0 + r0) * K + k0 + gl0 * 8;
        size_t gB1 = (size_t)(n0 + r1) * K + k0 + gl1 * 8;
        gload_lds16(Ah + gA0, sA_h + lb0);
        gload_lds16(Ah + gA1, sA_h + lb1);
        gload_lds16(Al + gA0, sA_l + lb0);
        gload_lds16(Al + gA1, sA_l + lb1);
        gload_lds16(Bh + gB0, sB_h + lb0);
        gload_lds16(Bh + gB1, sB_h + lb1);
        gload_lds16(Bl + gB0, sB_l + lb0);
        gload_lds16(Bl + gB1, sB_l + lb1);
        __syncthreads();

        #pragma unroll
        for (int pass = 0; pass < 3; ++pass) {
            const u16* sB_p = (pass == 2) ? sB_l : sB_h;
            const u16* sA_p = (pass == 1) ? sA_l : sA_h;
            v8bf bf[4];
            #pragma unroll
            for (int ni = 0; ni < 4; ++ni) {
                int r = wn + ni * 16 + fr;
                bf[ni] = *(const v8bf*)&sB_p[r * 32 + ((g ^ ((r >> 1) & 3)) << 3)];
            }
            #pragma unroll
            for (int mi = 0; mi < 4; ++mi) {
                int r = wm + mi * 16 + fr;
                v8bf af = *(const v8bf*)&sA_p[r * 32 + ((g ^ ((r >> 1) & 3)) << 3)];
                #pragma unroll
                for (int ni = 0; ni < 4; ++ni)
                    acc[mi][ni] = __builtin_amdgcn_mfma_f32_16x16x32_bf16(
                        af, bf[ni], acc[mi][ni], 0, 0, 0);
            }
        }
        __syncthreads();
    }

    int ocol = lane & 15;
    int orow = (lane >> 4) << 2;
    if (EPI == 1) {
        #pragma unroll
        for (int mi = 0; mi < 4; ++mi) {
            #pragma unroll
            for (int rr = 0; rr < 4; ++rr) {
                int m = m0 + wm + mi * 16 + orow + rr;
                #pragma unroll
                for (int ni = 0; ni < 4; ++ni) {
                    int n = n0 + wn + ni * 16 + ocol;
                    float v = acc[mi][ni][rr];
                    u16 h = f2bfu(v);
                    Chi[(size_t)m * N + n] = h;
                    Clo[(size_t)m * N + n] = f2bfu(v - bfu2f(h));
                }
            }
        }
    } else {
        float* Cz = C + (size_t)z * sC;
        float bb[4] = {0.f, 0.f, 0.f, 0.f};
        if (bias) {
            #pragma unroll
            for (int ni = 0; ni < 4; ++ni) bb[ni] = bias[n0 + wn + ni * 16 + ocol];
        }
        #pragma unroll
        for (int mi = 0; mi < 4; ++mi) {
            #pragma unroll
            for (int rr = 0; rr < 4; ++rr) {
                int m = m0 + wm + mi * 16 + orow + rr;
                #pragma unroll
                for (int ni = 0; ni < 4; ++ni) {
                    int n = n0 + wn + ni * 16 + ocol;
                    Cz[(size_t)m * N + n] = acc[mi][ni][rr] + bb[ni];
                }
            }
        }
    }
}

// ---------------------------------------------------------------------------
// fp32 -> bf16 hi/lo split, 4 elems per thread (exact-grid launch).
// ---------------------------------------------------------------------------
__global__ __launch_bounds__(256)
void convert_split(const float4* __restrict__ in,
                   ushort4* __restrict__ hi, ushort4* __restrict__ lo)
{
    size_t i = (size_t)blockIdx.x * 256 + threadIdx.x;
    float4 v = in[i];
    ushort4 h, l;
    h.x = f2bfu(v.x); l.x = f2bfu(v.x - bfu2f(h.x));
    h.y = f2bfu(v.y); l.y = f2bfu(v.y - bfu2f(h.y));
    h.z = f2bfu(v.z); l.z = f2bfu(v.z - bfu2f(h.z));
    h.w = f2bfu(v.w); l.w = f2bfu(v.w - bfu2f(h.w));
    hi[i] = h;
    lo[i] = l;
}

// ---------------------------------------------------------------------------
// Per-batch transpose of a bf16 hi/lo pair [b][T][D] -> [b][D][T].
// Packed u32 (hi|lo<<16) through a 32x33 LDS tile.
// ---------------------------------------------------------------------------
__global__ __launch_bounds__(256)
void transpose_pair(const u16* __restrict__ Sh, const u16* __restrict__ Sl,
                    u16* __restrict__ Th, u16* __restrict__ Tl)
{
    int b = blockIdx.z;
    const u16* XH = Sh + (size_t)b * T_SEQ * D_SZ;
    const u16* XL = Sl + (size_t)b * T_SEQ * D_SZ;
    u16* TH = Th + (size_t)b * T_SEQ * D_SZ;
    u16* TL = Tl + (size_t)b * T_SEQ * D_SZ;
    int t0 = blockIdx.x << 5, d0 = blockIdx.y << 5;

    __shared__ unsigned int tile[32][33];
    int tx = threadIdx.x & 31, ty = threadIdx.x >> 5;

    #pragma unroll
    for (int i = 0; i < 4; ++i) {
        int tt = ty + (i << 3);
        size_t off = (size_t)(t0 + tt) * D_SZ + d0 + tx;
        tile[tt][tx] = (unsigned int)XH[off] | ((unsigned int)XL[off] << 16);
    }
    __syncthreads();
    #pragma unroll
    for (int i = 0; i < 4; ++i) {
        int dd = ty + (i << 3);
        unsigned int v = tile[tx][dd];
        size_t off = (size_t)(d0 + dd) * T_SEQ + t0 + tx;
        TH[off] = (u16)(v & 0xffffu);
        TL[off] = (u16)(v >> 16);
    }
}

// ---------------------------------------------------------------------------
// Pack W_hh [4H,H] fp32 -> bf16 gate/k-pair packed (seq-fallback LSTM only).
// ---------------------------------------------------------------------------
__global__ __launch_bounds__(256)
void pack_whh_bf16(const float* __restrict__ Wf, const float* __restrict__ Wb,
                   uint4* __restrict__ Wpf, uint4* __restrict__ Wpb)
{
    int idx = blockIdx.x * 256 + threadIdx.x;
    int u = idx & (H_SZ - 1);
    int p = idx >> 8;
    uint4 a, b;
    unsigned int* pa = (unsigned int*)&a;
    unsigned int* pb = (unsigned int*)&b;
    #pragma unroll
    for (int g = 0; g < 4; ++g) {
        size_t row = (size_t)(g * H_SZ + u) * H_SZ;
        pa[g] = f2bf(Wf[row + 2 * p]) | (f2bf(Wf[row + 2 * p + 1]) << 16);
        pb[g] = f2bf(Wb[row + 2 * p]) | (f2bf(Wb[row + 2 * p + 1]) << 16);
    }
    Wpf[idx] = a;
    Wpb[idx] = b;
}

// ---------------------------------------------------------------------------
// Plain row-major bf16 cast of W_hh [1024,256] for the MFMA LSTM (both dirs).
// ---------------------------------------------------------------------------
__global__ __launch_bounds__(256)
void pack_w_rows(const float4* __restrict__ Wf, const float4* __restrict__ Wb,
                 ushort4* __restrict__ Of, ushort4* __restrict__ Ob)
{
    size_t i = (size_t)blockIdx.x * 256 + threadIdx.x;
    float4 a = Wf[i], b = Wb[i];
    ushort4 oa, ob;
    oa.x = f2bfu(a.x); oa.y = f2bfu(a.y); oa.z = f2bfu(a.z); oa.w = f2bfu(a.w);
    ob.x = f2bfu(b.x); ob.y = f2bfu(b.y); ob.z = f2bfu(b.z); ob.w = f2bfu(b.w);
    Of[i] = oa;
    Ob[i] = ob;
}

// ---------------------------------------------------------------------------
// MFMA LSTM recurrence, time-chunked (256 steps per dispatch).
// 4 blocks = 2 dirs x 2 groups of 16 batches. Per step per block:
//   gates[16,1024] = h[16,256] @ W^T via mfma_16x16x32 (M=16 exactly),
//   h as bf16 hi/lo split (~fp32), W bf16 streamed from L2 (0.5 MiB/dir).
// xg chunk is fp32 [b][256][1024] (accuracy identical to the seq path).
// h/c state persists across chunks in a small global buffer.
// ---------------------------------------------------------------------------
__global__ __launch_bounds__(512, 2)
void lstm_mfma(const float* __restrict__ xgF, const u16* __restrict__ WF,
               const float* __restrict__ xgB, const u16* __restrict__ WB,
               float* __restrict__ xe, float* __restrict__ stH,
               float* __restrict__ stC, int chunk)
{
    int bi  = blockIdx.x;          // 0..3
    int dir = bi >> 1;
    int b0  = (bi & 1) * 16;
    const float* xg = dir ? xgB : xgF;
    const u16*  W   = dir ? WB : WF;

    int tid  = threadIdx.x;
    int lane = tid & 63, wv = tid >> 6;
    int wn   = wv << 7;            // wave's 128-wide N-slice of 1024 gates
    int fr   = lane & 15;          // A row (batch) / B col-in-tile
    int kg   = lane >> 4;          // k-group (0..3)

    __shared__ u16  hHi[16 * 256];         //  8 KB, XOR-swizzled 16B slots
    __shared__ u16  hLo[16 * 256];         //  8 KB
    __shared__ float gate[16][1024 + 4];   // ~66 KB, stride 1028 (2-way only)

    // B pointers: 8 n-tiles per wave; k advances by imm offsets
    const u16* bp[8];
    #pragma unroll
    for (int ni = 0; ni < 8; ++ni)
        bp[ni] = W + (size_t)(wn + ni * 16 + fr) * 256 + kg * 8;

    // owner decomposition: thread = (u, bh); owns 8 local batches
    int u  = tid & 255;
    int bh = tid >> 8;
    float c8[8], hv8[8];
    #pragma unroll
    for (int j = 0; j < 8; ++j) {
        int bl = bh * 8 + j;
        float hv = 0.f, cv = 0.f;
        if (chunk != 0) {
            size_t si = (size_t)dir * 8192 + (size_t)(b0 + bl) * 256 + u;
            hv = stH[si];
            cv = stC[si];
        }
        c8[j] = cv; hv8[j] = hv;
        u16 hh = f2bfu(hv);
        u16 hl = f2bfu(hv - bfu2f(hh));
        int hoff = bl * 512 + (((u >> 3) ^ (bl & 7)) << 4) + ((u & 7) << 1);
        *(u16*)((char*)hHi + hoff) = hh;
        *(u16*)((char*)hLo + hoff) = hl;
    }
    __syncthreads();

    for (int sl = 0; sl < 256; ++sl) {
        int tc = dir ? (255 - sl) : sl;                       // row in chunk
        int t  = dir ? (1023 - 256 * chunk - sl) : (256 * chunk + sl);

        // owner xg prefetch (latency hidden under MFMA + B-stream)
        float pxi[8], pxf[8], pxg[8], pxo[8];
        #pragma unroll
        for (int j = 0; j < 8; ++j) {
            int bl = bh * 8 + j;
            const float* row = xg + ((size_t)(b0 + bl) * 256 + tc) * 1024;
            pxi[j] = row[u];
            pxf[j] = row[256 + u];
            pxg[j] = row[512 + u];
            pxo[j] = row[768 + u];
        }

        v4f accH[8], accL[8];
        #pragma unroll
        for (int ni = 0; ni < 8; ++ni) {
            accH[ni] = (v4f){0.f, 0.f, 0.f, 0.f};
            accL[ni] = (v4f){0.f, 0.f, 0.f, 0.f};
        }

        #pragma unroll
        for (int ks = 0; ks < 8; ++ks) {
            // A-frags from swizzled LDS: row=fr, slot = ks*4+kg, phys ^= fr&7
            int aoff = fr * 512 + ((((ks << 2) + kg) ^ (fr & 7)) << 4);
            v8bf aH = *(const v8bf*)((const char*)hHi + aoff);
            v8bf aL = *(const v8bf*)((const char*)hLo + aoff);
            #pragma unroll
            for (int ni = 0; ni < 8; ++ni) {
                v8bf bf = *(const v8bf*)(bp[ni] + ks * 32);
                accH[ni] = __builtin_amdgcn_mfma_f32_16x16x32_bf16(aH, bf, accH[ni], 0, 0, 0);
                accL[ni] = __builtin_amdgcn_mfma_f32_16x16x32_bf16(aL, bf, accL[ni], 0, 0, 0);
            }
        }

        // C-frag: row(batch) = 4*kg + reg, col(gate) = wn + ni*16 + fr
        int orow = kg << 2;
        #pragma unroll
        for (int ni = 0; ni < 8; ++ni) {
            #pragma unroll
            for (int r = 0; r < 4; ++r)
                gate[orow + r][wn + ni * 16 + fr] = accH[ni][r] + accL[ni][r];
        }
        __syncthreads();   // gates visible; all h reads of step done

        #pragma unroll
        for (int j = 0; j < 8; ++j) {
            int bl = bh * 8 + j;
            float ai = pxi[j] + gate[bl][u];
            float af = pxf[j] + gate[bl][256 + u];
            float ag = pxg[j] + gate[bl][512 + u];
            float ao = pxo[j] + gate[bl][768 + u];
            float ig = 1.f / (1.f + __expf(-ai));
            float fg = 1.f / (1.f + __expf(-af));
            float gv = tanh_fast(ag);
            float og = 1.f / (1.f + __expf(-ao));
            c8[j] = fg * c8[j] + ig * gv;
            float hv = og * tanh_fast(c8[j]);
            hv8[j] = hv;
            xe[((size_t)(b0 + bl) * T_SEQ + t) * D_SZ + dir * H_SZ + u] = hv;
            u16 hh = f2bfu(hv);
            u16 hl = f2bfu(hv - bfu2f(hh));
            int hoff = bl * 512 + (((u >> 3) ^ (bl & 7)) << 4) + ((u & 7) << 1);
            *(u16*)((char*)hHi + hoff) = hh;
            *(u16*)((char*)hLo + hoff) = hl;
        }
        __syncthreads();   // new h visible before next step's A-reads
    }

    // persist state for the next chunk
    #pragma unroll
    for (int j = 0; j < 8; ++j) {
        int bl = bh * 8 + j;
        size_t si = (size_t)dir * 8192 + (size_t)(b0 + bl) * 256 + u;
        stH[si] = hv8[j];
        stC[si] = c8[j];
    }
}

// ---------------------------------------------------------------------------
// Legacy LSTM (seq fallback path only).
// ---------------------------------------------------------------------------
__global__ __launch_bounds__(1024)
void lstm_bf16(const float* __restrict__ xgA, const uint4* __restrict__ WpA,
               const float* __restrict__ xgB, const uint4* __restrict__ WpB,
               float* __restrict__ xe, int d0, int fused)
{
    int i = blockIdx.x;
    int b, dir;
    if (fused) {
        int j = i & 7, m = i >> 3;
        dir = j >> 2;
        b   = (j & 3) * 8 + m;
    } else {
        b   = (i & 3) * 8 + (i >> 2);
        dir = d0;
    }
    const float* xg = dir ? xgB : xgA;
    const uint4* Wp = dir ? WpB : WpA;

    int tid   = threadIdx.x;
    int u     = tid & (H_SZ - 1);
    int slice = tid >> 8;
    int p0    = slice << 5;

    __shared__ float  hs[H_SZ];
    __shared__ float4 part[4][H_SZ];

    uint4 wres[16];
    {
        const uint4* wb = Wp + (size_t)p0 * H_SZ + u;
        #pragma unroll
        for (int q = 0; q < 16; ++q) wres[q] = wb[q * H_SZ];
    }
    const uint4* wstream = Wp + (size_t)(p0 + 16) * H_SZ + u;

    if (tid < H_SZ) hs[tid] = 0.f;
    float c = 0.f;
    __syncthreads();

    for (int s = 0; s < T_SEQ; ++s) {
        int t = dir ? (T_SEQ - 1 - s) : s;

        float xi = 0.f, xf = 0.f, xgv = 0.f, xo = 0.f;
        if (tid < H_SZ) {
            const float* row = xg + ((size_t)b * T_SEQ + t) * (4 * H_SZ);
            xi  = row[u];
            xf  = row[H_SZ + u];
            xgv = row[2 * H_SZ + u];
            xo  = row[3 * H_SZ + u];
        }

        float4 acc; acc.x = 0.f; acc.y = 0.f; acc.z = 0.f; acc.w = 0.f;

        #define DOT_PAIR(WQ, P)                                             \
        {                                                                   \
            float2 hp = *(const float2*)&hs[2 * (P)];                       \
            const unsigned int* wc = (const unsigned int*)&(WQ);            \
            _Pragma("unroll")                                               \
            for (int g = 0; g < 4; ++g) {                                   \
                float wlo = __uint_as_float(wc[g] << 16);                   \
                float whi = __uint_as_float(wc[g] & 0xffff0000u);           \
                ((float*)&acc)[g] =                                         \
                    fmaf(whi, hp.y, fmaf(wlo, hp.x, ((float*)&acc)[g]));    \
            }                                                               \
        }

        #pragma unroll
        for (int q = 0; q < 16; ++q) {
            DOT_PAIR(wres[q], p0 + q);
        }
        #pragma unroll
        for (int q = 0; q < 16; ++q) {
            int qr = (q + s) & 15;
            uint4 wq = wstream[(size_t)qr * H_SZ];
            DOT_PAIR(wq, p0 + 16 + qr);
        }
        #undef DOT_PAIR

        part[slice][u] = acc;
        __syncthreads();

        if (tid < H_SZ) {
            float4 pp0 = part[0][u], pp1 = part[1][u], pp2 = part[2][u], pp3 = part[3][u];
            float ai = xi  + pp0.x + pp1.x + pp2.x + pp3.x;
            float af = xf  + pp0.y + pp1.y + pp2.y + pp3.y;
            float ag = xgv + pp0.z + pp1.z + pp2.z + pp3.z;
            float ao = xo  + pp0.w + pp1.w + pp2.w + pp3.w;
            float ig = 1.f / (1.f + __expf(-ai));
            float fg = 1.f / (1.f + __expf(-af));
            float gg = tanh_fast(ag);
            float og = 1.f / (1.f + __expf(-ao));
            c = fg * c + ig * gg;
            float h = og * tanh_fast(c);
            hs[u] = h;
            xe[((size_t)b * T_SEQ + t) * D_SZ + dir * H_SZ + u] = h;
        }
        __syncthreads();
    }
}

// ---------------------------------------------------------------------------
// Masked row softmax (fp32 in place); row0 = global row of L's first row.
// ---------------------------------------------------------------------------
__global__ __launch_bounds__(256)
void softmax_rows(float* __restrict__ L, const void* __restrict__ maskraw,
                  int row0)
{
    const unsigned char* mu8 = (const unsigned char*)maskraw;
    const int*           mi32 = (const int*)maskraw;
    bool layout_u8 = (mu8[1023] != 0);

    int lane = threadIdx.x & 63;
    int wid  = threadIdx.x >> 6;
    int row  = (blockIdx.x << 2) + wid;
    float* p = L + (size_t)row * T_SEQ;

    int grow = row0 + row;
    int mval = layout_u8 ? (int)mu8[grow] : mi32[grow];

    if (mval != 0) {
        const float inv = 1.0f / (float)T_SEQ;
        for (int j = lane; j < T_SEQ; j += 64) p[j] = inv;
        return;
    }

    float v[16];
    float m = -1e30f;
    #pragma unroll
    for (int u = 0; u < 16; ++u) {
        v[u] = p[lane + (u << 6)];
        m = fmaxf(m, v[u]);
    }
    #pragma unroll
    for (int s = 32; s; s >>= 1) m = fmaxf(m, __shfl_xor(m, s, 64));

    float sum = 0.f;
    #pragma unroll
    for (int u = 0; u < 16; ++u) {
        v[u] = __expf(v[u] - m);
        sum += v[u];
    }
    #pragma unroll
    for (int s = 32; s; s >>= 1) sum += __shfl_xor(sum, s, 64);

    float inv = 1.0f / sum;
    #pragma unroll
    for (int u = 0; u < 16; ++u) p[lane + (u << 6)] = v[u] * inv;
}

// ---------------------------------------------------------------------------
// Fused path, fits ws = 192 MiB (R5 discovery: ws in [192,320) MiB — the old
// 320 MiB fused path NEVER ran; the seq fallback did, every round).
// Regions (MiB): A=[0,64) B=[64,128) C=[128,192).
//   chunked LSTM phase: A = x pair (persists); B = xgf chunk fp32 [64,96) +
//     xgb chunk fp32 [96,128) (32 MiB each, 256 steps); C = xe fp32.
//   attention phase: A = xe pair ([0,32),[32,64)); B = xeT pair; C per
//     batch-quarter q (8 batches): pj pair [128,136)+[136,144), L fp32
//     [144,176), L_hi [176,192), L_lo [128,144) (pj dead).
// d_out scratch (dead before the final out-GEMM quarter that overwrites it):
//   Wihf pair [1,3), Wihb pair [3,5) (dead before out q0 writes [0,16));
//   WB_f/WB_b [60,61), state h/c [61,61.2) (dead before out q3 writes
//   [48,64)); Wl pair [63,64) (last read pj q3, before out q3).
// All scratch is re-written at the top of every launch (graph-replay safe).
// ---------------------------------------------------------------------------
extern "C" void kernel_launch(void* const* d_in, const int* in_sizes, int n_in,
                              void* d_out, int out_size, void* d_ws, size_t ws_size,
                              hipStream_t stream)
{
    const float* x     = (const float*)d_in[0];
    const void*  xmask = d_in[1];
    const float* Wih_f = (const float*)d_in[2];
    const float* Whh_f = (const float*)d_in[3];
    const float* b_f   = (const float*)d_in[4];
    const float* Wih_b = (const float*)d_in[5];
    const float* Whh_b = (const float*)d_in[6];
    const float* b_b   = (const float*)d_in[7];
    const float* W_l   = (const float*)d_in[8];
    float* out = (float*)d_out;

    char* ws = (char*)d_ws;
    const size_t MB1 = (size_t)1 << 20;
    const size_t SZ_XE = (size_t)B_SZ * T_SEQ * D_SZ * sizeof(float);      //  64 MiB
    const size_t SZ_XG = (size_t)B_SZ * T_SEQ * 4 * H_SZ * sizeof(float);  // 128 MiB
    bool fused = ws_size >= 192 * MB1;

    const int MT = B_SZ * T_SEQ;                       // 32768
    const long long sTD = (long long)T_SEQ * D_SZ;     // 524288
    const long long sTT = (long long)T_SEQ * T_SEQ;    // 1048576

    if (fused) {
        u16*  x_hi  = (u16*)(ws);                      // A
        u16*  x_lo  = (u16*)(ws + 32 * MB1);
        float* xg_f = (float*)(ws + 64 * MB1);         // B (chunk, 32 MiB)
        float* xg_b = (float*)(ws + 96 * MB1);
        float* xe   = (float*)(ws + 128 * MB1);        // C
        u16*  xe_hi = (u16*)(ws);                      // A after LSTM
        u16*  xe_lo = (u16*)(ws + 32 * MB1);
        u16*  xT_hi = (u16*)(ws + 64 * MB1);           // B after LSTM
        u16*  xT_lo = (u16*)(ws + 96 * MB1);
        u16*  pj_hi = (u16*)(ws + 128 * MB1);          // C quarter loop
        u16*  pj_lo = (u16*)(ws + 136 * MB1);
        float* L    = (float*)(ws + 144 * MB1);        // 32 MiB (8 batches)
        u16*  L_hi  = (u16*)(ws + 176 * MB1);
        u16*  L_lo  = (u16*)(ws + 128 * MB1);          // reuse pj region

        u16* Wihf_hi = (u16*)((char*)d_out + 1 * MB1);
        u16* Wihf_lo = (u16*)((char*)d_out + 2 * MB1);
        u16* Wihb_hi = (u16*)((char*)d_out + 3 * MB1);
        u16* Wihb_lo = (u16*)((char*)d_out + 4 * MB1);
        u16* WB_f    = (u16*)((char*)d_out + 60 * MB1);
        u16* WB_b    = (u16*)((char*)d_out + 60 * MB1 + (MB1 >> 1));
        float* stH   = (float*)((char*)d_out + 61 * MB1);
        float* stC   = (float*)((char*)d_out + 61 * MB1 + 65536);
        u16* Wl_hi   = (u16*)((char*)d_out + 63 * MB1);
        u16* Wl_lo   = (u16*)((char*)d_out + 63 * MB1 + (MB1 >> 1));

        // 1. packs/splits
        convert_split<<<dim3((MT * D_SZ) / 1024), dim3(256), 0, stream>>>(
            (const float4*)x, (ushort4*)x_hi, (ushort4*)x_lo);
        pack_w_rows<<<dim3((4 * H_SZ * H_SZ) / 1024), dim3(256), 0, stream>>>(
            (const float4*)Whh_f, (const float4*)Whh_b,
            (ushort4*)WB_f, (ushort4*)WB_b);
        convert_split<<<dim3((4 * H_SZ * D_SZ) / 1024), dim3(256), 0, stream>>>(
            (const float4*)Wih_f, (ushort4*)Wihf_hi, (ushort4*)Wihf_lo);
        convert_split<<<dim3((4 * H_SZ * D_SZ) / 1024), dim3(256), 0, stream>>>(
            (const float4*)Wih_b, (ushort4*)Wihb_hi, (ushort4*)Wihb_lo);
        convert_split<<<dim3((D_SZ * D_SZ) / 1024), dim3(256), 0, stream>>>(
            (const float4*)W_l, (ushort4*)Wl_hi, (ushort4*)Wl_lo);

        // 2. time-chunked BiLSTM: per chunk, xg for 256 steps (fp32) + MFMA
        //    recurrence. fwd chunk c: t in [256c,256c+256);
        //    bwd chunk c: t in [768-256c, 1024-256c).
        for (int c = 0; c < 4; ++c) {
            int tbF = 256 * c;
            int tbB = 768 - 256 * c;
            gemm_ms<0><<<dim3(8, 2, B_SZ), dim3(256), 0, stream>>>(
                x_hi + (size_t)tbF * D_SZ, x_lo + (size_t)tbF * D_SZ,
                Wihf_hi, Wihf_lo, b_f, xg_f, nullptr, nullptr,
                256, 4 * H_SZ, D_SZ, sTD, 0, 256LL * 1024);
            gemm_ms<0><<<dim3(8, 2, B_SZ), dim3(256), 0, stream>>>(
                x_hi + (size_t)tbB * D_SZ, x_lo + (size_t)tbB * D_SZ,
                Wihb_hi, Wihb_lo, b_b, xg_b, nullptr, nullptr,
                256, 4 * H_SZ, D_SZ, sTD, 0, 256LL * 1024);
            lstm_mfma<<<dim3(4), dim3(512), 0, stream>>>(
                xg_f, WB_f, xg_b, WB_b, xe, stH, stC, c);
        }

        // 3. xe -> hi/lo pair (A; x pair dead), then transpose pair (B)
        convert_split<<<dim3((MT * D_SZ) / 1024), dim3(256), 0, stream>>>(
            (const float4*)xe, (ushort4*)xe_hi, (ushort4*)xe_lo);
        transpose_pair<<<dim3(T_SEQ / 32, D_SZ / 32, B_SZ), dim3(256), 0, stream>>>(
            xe_hi, xe_lo, xT_hi, xT_lo);

        // 4. attention in 4 batch-quarters (8 batches each, L fits C)
        for (int q = 0; q < 4; ++q) {
            size_t boff = (size_t)q * 8 * sTD;
            // pj = xe @ W_l^T (pair out)
            gemm_ms<1><<<dim3(D_SZ / 128, (8 * T_SEQ) / 128, 1), dim3(256), 0, stream>>>(
                xe_hi + boff, xe_lo + boff, Wl_hi, Wl_lo, nullptr,
                nullptr, pj_hi, pj_lo, 8 * T_SEQ, D_SZ, D_SZ, 0, 0, 0);
            // L = pj @ xe^T (fp32)
            gemm_ms<0><<<dim3(T_SEQ / 128, T_SEQ / 128, 8), dim3(256), 0, stream>>>(
                pj_hi, pj_lo, xe_hi + boff, xe_lo + boff, nullptr,
                L, nullptr, nullptr, T_SEQ, T_SEQ, D_SZ, sTD, sTD, sTT);
            // masked softmax in place
            softmax_rows<<<dim3((8 * T_SEQ) / 4), dim3(256), 0, stream>>>(
                L, xmask, q * 8 * T_SEQ);
            // L -> pair (L_lo overwrites dead pj)
            convert_split<<<dim3((8 * T_SEQ * T_SEQ) / 1024), dim3(256), 0, stream>>>(
                (const float4*)L, (ushort4*)L_hi, (ushort4*)L_lo);
            // out = A @ xe  ==  NT(L pair, xeT pair)
            gemm_ms<0><<<dim3(D_SZ / 128, T_SEQ / 128, 8), dim3(256), 0, stream>>>(
                L_hi, L_lo, xT_hi + boff, xT_lo + boff, nullptr,
                out + boff, nullptr, nullptr, T_SEQ, D_SZ, T_SEQ, sTT, sTD, sTD);
        }
    } else {
        // -------- fp32 fallback (ws < 192 MiB; previous-session structure) --
        uint4* Wpf = (uint4*)d_out;
        uint4* Wpb = (uint4*)d_out + 128 * H_SZ;
        float* xe   = (float*)(ws);
        float* xg_f = (float*)(ws + SZ_XE);
        float* xg_b = xg_f;
        float* L    = xg_f;
        float* proj = out;

        pack_whh_bf16<<<dim3((128 * H_SZ) / 256), dim3(256), 0, stream>>>(
            Whh_f, Whh_b, Wpf, Wpb);
        gemm_nt<<<dim3((4 * H_SZ) / BN, MT / BM, 1), dim3(256), 0, stream>>>(
            x, Wih_f, b_f, xg_f, MT, 4 * H_SZ, D_SZ, 0, 0, 0);
        lstm_bf16<<<dim3(B_SZ), dim3(1024), 0, stream>>>(
            xg_f, Wpf, xg_f, Wpf, xe, 0, 0);
        gemm_nt<<<dim3((4 * H_SZ) / BN, MT / BM, 1), dim3(256), 0, stream>>>(
            x, Wih_b, b_b, xg_b, MT, 4 * H_SZ, D_SZ, 0, 0, 0);
        lstm_bf16<<<dim3(B_SZ), dim3(1024), 0, stream>>>(
            xg_b, Wpb, xg_b, Wpb, xe, 1, 0);

        gemm_nt<<<dim3(D_SZ / BN, MT / BM, 1), dim3(256), 0, stream>>>(
            xe, W_l, nullptr, proj, MT, D_SZ, D_SZ, 0, 0, 0);
        gemm_nt<<<dim3(T_SEQ / BN, T_SEQ / BM, B_SZ), dim3(256), 0, stream>>>(
            proj, xe, nullptr, L, T_SEQ, T_SEQ, D_SZ, sTD, sTD, sTT);
        softmax_rows<<<dim3(MT / 4), dim3(256), 0, stream>>>(L, xmask, 0);
        gemm_nn<<<dim3(D_SZ / BN, T_SEQ / BM, B_SZ), dim3(256), 0, stream>>>(
            L, xe, out, T_SEQ, D_SZ, T_SEQ, sTT, sTD, sTD);
    }
}